// Round 12
// baseline (690.589 us; speedup 1.0000x reference)
//
#include <hip/hip_runtime.h>
#include <stdint.h>

// SNN: conv(2->8,3x3,SAME on 512x32) -> LIF(T=4) -> FC 131072->512 -> LIF
//      -> FC 512->512 -> LIF -> mean over T -> FC 512->16
// All fp32 I/O. tau=2: v = 0.5*v + x; spike v>=1; hard reset to 0.
//
// Output layout (concat, fp32):
//   out:        (128,16)            @ 0
//   conv_spk:   (128,4,8,512,32)    @ 2048
//   input_spk:  (128,4,512)         @ 67110912
//   hidden_spk: (128,4,512)         @ 67373056

#define OFF_CONV  2048ll
#define OFF_IN    67110912ll
#define OFF_HID   67373056ll

typedef short bf16x8 __attribute__((ext_vector_type(8)));
typedef float f32x4  __attribute__((ext_vector_type(4)));

__device__ __forceinline__ unsigned short f2bf(float f) {
  unsigned u = __float_as_uint(f);
  u += 0x7FFFu + ((u >> 16) & 1u);   // round-to-nearest-even to bf16
  return (unsigned short)(u >> 16);
}

// expand 4 spike bits (byte lanes of x, bit t already shifted to bit0 of each
// byte) -> two dwords of packed bf16 {0,1}
__device__ __forceinline__ void expand2(unsigned x, unsigned& o0, unsigned& o1) {
  // x = b0 | b1<<8 | b2<<16 | b3<<24, each 0/1
  o0 = (x & 1u) * 0x3F80u | (x & 0x100u) * 0x3F8000u;
  unsigned y = x >> 16;
  o1 = (y & 1u) * 0x3F80u | (y & 0x100u) * 0x3F8000u;
}

// ---------------------------------------------------------------------------
// Kernel 1: conv + LIF over T=4. (round-3 verified)
// ---------------------------------------------------------------------------
__global__ __launch_bounds__(256) void conv_lif_kernel(
    const float* __restrict__ x, const float* __restrict__ wc,
    float* __restrict__ out, unsigned char* __restrict__ patt)
{
  __shared__ float wcs[144];
  int tid = threadIdx.x;
  if (tid < 144) wcs[tid] = wc[tid];
  __syncthreads();

  int idx = blockIdx.x * 256 + tid;        // b*32768 + co*4096 + h*8 + wq
  int b   = idx >> 15;
  int k4  = idx & 32767;
  int co  = k4 >> 12;
  int rem = k4 & 4095;
  int h   = rem >> 3;
  int w0  = (rem & 7) * 4;

  const float* xb = x + (long long)b * 32768;  // (2, 512, 32) per batch
  float c[4] = {0.f, 0.f, 0.f, 0.f};
#pragma unroll
  for (int ci = 0; ci < 2; ++ci) {
    const float* xc = xb + ci * 16384;
    const float* wk = wcs + co * 18 + ci * 9;
    float win[3][6];
#pragma unroll
    for (int r = 0; r < 3; ++r) {
      int hh = h - 1 + r;
      if (hh >= 0 && hh < 512) {
        const float* row = xc + hh * 32;
        float4 m = *(const float4*)(row + w0);
        win[r][1] = m.x; win[r][2] = m.y; win[r][3] = m.z; win[r][4] = m.w;
        win[r][0] = (w0 > 0)  ? row[w0 - 1] : 0.f;
        win[r][5] = (w0 < 28) ? row[w0 + 4] : 0.f;
      } else {
#pragma unroll
        for (int j = 0; j < 6; ++j) win[r][j] = 0.f;
      }
    }
#pragma unroll
    for (int r = 0; r < 3; ++r)
#pragma unroll
      for (int dw = 0; dw < 3; ++dw) {
        float wgt = wk[r * 3 + dw];
#pragma unroll
        for (int j = 0; j < 4; ++j) c[j] += win[r][j + dw] * wgt;
      }
  }

  int k = co * 16384 + h * 32 + w0;
  float* ob = out + OFF_CONV + (long long)b * 524288 + k;
  float v[4] = {0.f, 0.f, 0.f, 0.f};
  unsigned p[4] = {0, 0, 0, 0};
#pragma unroll
  for (int t = 0; t < 4; ++t) {
    f32x4 sv;
#pragma unroll
    for (int j = 0; j < 4; ++j) {
      v[j] = v[j] * 0.5f + c[j];
      int si = (v[j] >= 1.0f) ? 1 : 0;
      sv[j] = (float)si;
      if (si) v[j] = 0.f;
      p[j] |= (unsigned)si << t;
    }
    __builtin_nontemporal_store(sv, (f32x4*)(ob + t * 131072));
  }
  unsigned pb = p[0] | (p[1] << 8) | (p[2] << 16) | (p[3] << 24);
  *(unsigned*)(patt + (long long)b * 131072 + k) = pb;
}

// ---------------------------------------------------------------------------
// Kernel 2: transpose w2 (512x512) -> w2t (round-3 verified)
// ---------------------------------------------------------------------------
__global__ __launch_bounds__(256) void transpose512(
    const float* __restrict__ w2, float* __restrict__ w2t)
{
  __shared__ float tile[32][33];
  int bx = blockIdx.x & 15, by = blockIdx.x >> 4;
  int tx = threadIdx.x & 31, ty = threadIdx.x >> 5;  // 32 x 8
#pragma unroll
  for (int i = 0; i < 32; i += 8)
    tile[ty + i][tx] = w2[(by * 32 + ty + i) * 512 + bx * 32 + tx];
  __syncthreads();
#pragma unroll
  for (int i = 0; i < 32; i += 8)
    w2t[(bx * 32 + ty + i) * 512 + by * 32 + tx] = tile[tx][ty + i];
}

// ---------------------------------------------------------------------------
// Kernel 3 v6: GEMM Z1[t*128+b][n] = sum_k spike[t][b][k] * w1[n][k]
//
// ONE BARRIER PER STEP (v5.1 post-mortem: v4 ~124us == v5.1 ~125us despite
// -40% LDS traffic -> NOT LDS-bound; step = 4700cy vs 2483 MFMA floor. The
// gap is the 2-barrier lockstep: stage VALU on the critical path + vmcnt(0)
// drain at BOTH barriers). v6 = parity double-buffered LDS (T3 minimum
// 2-phase recipe): per step s:
//   [issue loads s+2] [STAGE s+1 -> buf^1] [MFMA from buf] [barrier]
// Loads get the whole STAGE+MFMA phase (~2500cy > 900cy HBM) before the
// end-of-step drain; stage overlaps the co-block's MFMA.
// Race audit: buf B is read in step s(buf==B) pre-barrier_s; written in
// step s+1 post-barrier_s. Reg set [s&1] is reloaded in step s only after
// its contents were staged in step s-1 (pre-barrier_{s-1}).
// Data path identical to v5.1 (packed-patt A in LDS, per-wave in-register
// expand of own t; B hi/lo bf16). Same MFMA sequence per acc -> bitwise
// identical. LDS 2x16.4 = 32.9 KB -> still 2 blocks/CU (VGPR-capped).
// Grid: bid = nt*S + chunk (nt-siblings differ by S=64, 64%8==0 -> same XCD).
// ---------------------------------------------------------------------------
__global__ __launch_bounds__(256, 2) void gemm_kernel(
    const unsigned char* __restrict__ patt, const float* __restrict__ w1,
    float* __restrict__ partials, int steps)
{
  __shared__ __attribute__((aligned(16))) unsigned char  AsP[2][128][48];
  __shared__ __attribute__((aligned(16))) unsigned short Bh[2][64][40];
  __shared__ __attribute__((aligned(16))) unsigned short Bl[2][64][40];

  const int tid   = threadIdx.x;
  const int S     = gridDim.x >> 3;          // split-K chunks
  const int nt    = blockIdx.x / S;          // N-tile (64 w1 rows), 0..7
  const int chunk = blockIdx.x - nt * S;     // split-K chunk
  const long long k0 = (long long)chunk * steps * 32;

  // A staging: 128 rows x 16 patt bytes per thread (pure copy)
  const int ra  = tid >> 1;                  // 0..127
  const int koa = (tid & 1) * 16;            // 0,16 (16-aligned with 48B rows)
  const unsigned char* pA = patt + (long long)ra * 131072 + k0 + koa;

  // B staging: 64 rows x 8 floats per thread
  const int rb  = tid >> 2;                  // 0..63
  const int kob = (tid & 3) * 8;             // 0,8,16,24 (floats/shorts)
  const float* pB = w1 + (long long)(nt * 64 + rb) * 131072 + k0 + kob;

  const int lane = tid & 63;
  const int t    = tid >> 6;                 // wave id == timestep 0..3
  const int l15 = lane & 15, quad = lane >> 4;

  f32x4 acc[8][4];
#pragma unroll
  for (int i = 0; i < 8; ++i)
#pragma unroll
    for (int j = 0; j < 4; ++j) acc[i][j] = (f32x4){0.f, 0.f, 0.f, 0.f};

  // two raw-register staging sets (parity: set[(s+1)&1] holds step-s+1 data)
  uint4 pa[2]; float4 f0[2], f1[2];

#define STAGE(bb, PP, F0, F1)                                              \
  {                                                                        \
    *(uint4*)&AsP[bb][ra][koa] = (PP);                                     \
    float fv[8] = {(F0).x, (F0).y, (F0).z, (F0).w,                         \
                   (F1).x, (F1).y, (F1).z, (F1).w};                        \
    unsigned hp[4], lp[4];                                                 \
    _Pragma("unroll")                                                      \
    for (int i = 0; i < 4; ++i) {                                          \
      unsigned short h0 = f2bf(fv[2 * i]);                                 \
      unsigned short h1 = f2bf(fv[2 * i + 1]);                             \
      float r0 = fv[2 * i]     - __uint_as_float((unsigned)h0 << 16);      \
      float r1 = fv[2 * i + 1] - __uint_as_float((unsigned)h1 << 16);      \
      hp[i] = (unsigned)h0 | ((unsigned)h1 << 16);                         \
      lp[i] = (unsigned)f2bf(r0) | ((unsigned)f2bf(r1) << 16);             \
    }                                                                      \
    *(uint4*)&Bh[bb][rb][kob] = make_uint4(hp[0], hp[1], hp[2], hp[3]);    \
    *(uint4*)&Bl[bb][rb][kob] = make_uint4(lp[0], lp[1], lp[2], lp[3]);    \
  }

  // prologue: load step 0 regs -> stage into buf 0; load step 1 regs
  pa[0] = *(const uint4*)pA;
  f0[0] = *(const float4*)pB;
  f1[0] = *(const float4*)(pB + 4);
  STAGE(0, pa[0], f0[0], f1[0]);
  if (steps > 1) {
    pa[1] = *(const uint4*)(pA + 32);        // +32 BYTES  = step 1 patt
    f0[1] = *(const float4*)(pB + 32);       // +32 FLOATS = step 1 w1
    f1[1] = *(const float4*)(pB + 36);
  }
  __syncthreads();

  for (int s = 0; s < steps; ++s) {
    const int cur = s & 1;        // LDS buffer holding step s
    const int nxt = (s + 1) & 1;  // reg set holding step s+1 raw data

    // issue loads for step s+2 into the dead reg set [s&1]
    if (s + 2 < steps) {
      pa[cur] = *(const uint4*)(pA + (long long)(s + 2) * 32);
      f0[cur] = *(const float4*)(pB + (long long)(s + 2) * 32);
      f1[cur] = *(const float4*)(pB + (long long)(s + 2) * 32 + 4);
    }

    // stage step s+1 into the other LDS buffer (pre-barrier: its readers
    // finished last step, before the previous barrier)
    if (s + 1 < steps) STAGE(nxt, pa[nxt], f0[nxt], f1[nxt]);

    // B fragments for step s (shared across fm)
    bf16x8 bh[4], bl[4];
#pragma unroll
    for (int fn = 0; fn < 4; ++fn) {
      bh[fn] = *(const bf16x8*)&Bh[cur][fn * 16 + l15][quad * 8];
      bl[fn] = *(const bf16x8*)&Bl[cur][fn * 16 + l15][quad * 8];
    }

    __builtin_amdgcn_s_setprio(1);
#pragma unroll
    for (int fm = 0; fm < 8; ++fm) {
      // read 8 packed patt bytes, expand bit t in-register -> bf16x8 {0,1}
      uint2 ap = *(const uint2*)&AsP[cur][fm * 16 + l15][quad * 8];
      unsigned x0 = (ap.x >> t) & 0x01010101u;
      unsigned x1 = (ap.y >> t) & 0x01010101u;
      unsigned o0, o1, o2, o3;
      expand2(x0, o0, o1);
      expand2(x1, o2, o3);
      union { uint4 u; bf16x8 v; } au;
      au.u = make_uint4(o0, o1, o2, o3);
      bf16x8 a = au.v;
#pragma unroll
      for (int fn = 0; fn < 4; ++fn) {
        acc[fm][fn] = __builtin_amdgcn_mfma_f32_16x16x32_bf16(a, bh[fn], acc[fm][fn], 0, 0, 0);
        acc[fm][fn] = __builtin_amdgcn_mfma_f32_16x16x32_bf16(a, bl[fn], acc[fm][fn], 0, 0, 0);
      }
    }
    __builtin_amdgcn_s_setprio(0);

    __syncthreads();  // ONE barrier: buf nxt fully staged; buf cur free
  }
#undef STAGE

  // epilogue: partials[chunk][t*128+b][n]; D: row = quad*4+reg (b), col = l15
  float* pc = partials + (long long)chunk * 262144;
#pragma unroll
  for (int fm = 0; fm < 8; ++fm)
#pragma unroll
    for (int fn = 0; fn < 4; ++fn) {
      int m = t * 128 + fm * 16 + quad * 4;
      int n = nt * 64 + fn * 16 + l15;
#pragma unroll
      for (int rg = 0; rg < 4; ++rg)
        pc[(long long)(m + rg) * 512 + n] = acc[fm][fn][rg];
    }
}

// ---------------------------------------------------------------------------
// Kernel 4a/4b: two-stage split-K reduce (round-11 verified, absmax 0.0).
// partial2 lives in the dead patt region (gemm finished before reduce).
// ---------------------------------------------------------------------------
__global__ __launch_bounds__(256) void reduce1_kernel(
    const float* __restrict__ partials, float* __restrict__ p2)
{
  int tg = blockIdx.x * 256 + threadIdx.x;   // G*65536 threads
  int item = tg & 65535;
  int g = tg >> 16;
  const float* src = partials + (long long)g * 8 * 262144 + item * 4;
  float4 a = {0.f, 0.f, 0.f, 0.f};
#pragma unroll
  for (int c = 0; c < 8; ++c) {
    float4 p = *(const float4*)(src + (long long)c * 262144);
    a.x += p.x; a.y += p.y; a.z += p.z; a.w += p.w;
  }
  *(float4*)(p2 + (long long)g * 262144 + item * 4) = a;
}

__global__ __launch_bounds__(256) void reduce2_kernel(
    const float* __restrict__ p2, float* __restrict__ z1, int G)
{
  int item = blockIdx.x * 256 + threadIdx.x;  // 65536
  float4 a = {0.f, 0.f, 0.f, 0.f};
  for (int g = 0; g < G; ++g) {
    float4 p = *(const float4*)(p2 + (long long)g * 262144 + item * 4);
    a.x += p.x; a.y += p.y; a.z += p.z; a.w += p.w;
  }
  *(float4*)(z1 + item * 4) = a;
}

// fallback single-stage (S < 8)
__global__ __launch_bounds__(256) void reduce_kernel(
    const float* __restrict__ partials, float* __restrict__ z1, int S)
{
  int idx = (blockIdx.x * 256 + threadIdx.x) * 4;
  float4 a = {0.f, 0.f, 0.f, 0.f};
  for (int c = 0; c < S; ++c) {
    float4 p = *(const float4*)(partials + (long long)c * 262144 + idx);
    a.x += p.x; a.y += p.y; a.z += p.z; a.w += p.w;
  }
  *(float4*)(z1 + idx) = a;
}

// ---------------------------------------------------------------------------
// Kernel 5: per-batch FC pipeline (round-3 verified): LIF1 -> sparse FC2 ->
// LIF2 -> mean -> readout. Sparse skip of exact-0 terms is a bitwise fp32
// identity; ascending-k order preserved.
// ---------------------------------------------------------------------------
__global__ __launch_bounds__(512) void fc_kernel(
    const float* __restrict__ z1, const float* __restrict__ w2t,
    const float* __restrict__ wout, float* __restrict__ out)
{
  int b = blockIdx.x;
  int n = threadIdx.x;
  __shared__ float s1s[512];
  __shared__ float red[512];
  __shared__ unsigned short idxs[512];
  __shared__ int cnts[8];

  const int wid = n >> 6, lane = n & 63;

  float v1 = 0.f, v2 = 0.f, ssum = 0.f;
#pragma unroll
  for (int t = 0; t < 4; ++t) {
    float z = z1[((t * 128 + b) << 9) + n];
    v1 = v1 * 0.5f + z;
    float s1 = (v1 >= 1.0f) ? 1.f : 0.f;
    out[OFF_IN + ((long long)b * 4 + t) * 512 + n] = s1;
    if (s1 != 0.f) v1 = 0.f;

    unsigned long long m = __ballot(s1 != 0.f);
    if (lane == 0) cnts[wid] = __popcll(m);
    __syncthreads();
    int base = 0, total = 0;
#pragma unroll
    for (int w = 0; w < 8; ++w) {
      int c = cnts[w];
      base  += (w < wid) ? c : 0;
      total += c;
    }
    if (s1 != 0.f) {
      int pos = base + (int)__popcll(m & ((1ull << lane) - 1ull));
      idxs[pos] = (unsigned short)n;
    }
    __syncthreads();

    float z2 = 0.f;
    int j = 0;
    for (; j + 8 <= total; j += 8) {
      float a0 = w2t[((int)idxs[j + 0] << 9) + n];
      float a1 = w2t[((int)idxs[j + 1] << 9) + n];
      float a2 = w2t[((int)idxs[j + 2] << 9) + n];
      float a3 = w2t[((int)idxs[j + 3] << 9) + n];
      float a4 = w2t[((int)idxs[j + 4] << 9) + n];
      float a5 = w2t[((int)idxs[j + 5] << 9) + n];
      float a6 = w2t[((int)idxs[j + 6] << 9) + n];
      float a7 = w2t[((int)idxs[j + 7] << 9) + n];
      z2 += a0; z2 += a1; z2 += a2; z2 += a3;
      z2 += a4; z2 += a5; z2 += a6; z2 += a7;
    }
    for (; j < total; ++j)
      z2 += w2t[((int)idxs[j] << 9) + n];

    v2 = v2 * 0.5f + z2;
    float s2 = (v2 >= 1.0f) ? 1.f : 0.f;
    out[OFF_HID + ((long long)b * 4 + t) * 512 + n] = s2;
    if (s2 != 0.f) v2 = 0.f;
    ssum += s2;
    __syncthreads();
  }

  s1s[n] = ssum * 0.25f;
  __syncthreads();

  int o = n & 15, part = n >> 4;
  float p = 0.f;
#pragma unroll
  for (int j = 0; j < 16; ++j)
    p += s1s[part * 16 + j] * wout[o * 512 + part * 16 + j];
  red[n] = p;
  __syncthreads();
  if (n < 16) {
    float a = 0.f;
#pragma unroll
    for (int pp = 0; pp < 32; ++pp) a += red[pp * 16 + n];
    out[b * 16 + n] = a;
  }
}

// ---------------------------------------------------------------------------
extern "C" void kernel_launch(void* const* d_in, const int* in_sizes, int n_in,
                              void* d_out, int out_size, void* d_ws, size_t ws_size,
                              hipStream_t stream) {
  const float* x     = (const float*)d_in[0];
  const float* wconv = (const float*)d_in[1];
  const float* w1    = (const float*)d_in[2];
  const float* w2    = (const float*)d_in[3];
  const float* wout  = (const float*)d_in[4];
  float* out = (float*)d_out;
  char* ws = (char*)d_ws;

  unsigned char* patt = (unsigned char*)ws;                 // 16 MB
  float* w2t      = (float*)(ws + 16777216);                // 1 MB
  float* z1       = (float*)(ws + 16777216 + 1048576);      // 1 MB
  float* partials = (float*)(ws + 16777216 + 2097152);      // S MB
  float* p2       = (float*)ws;   // reuse dead patt region (gemm done)

  int S = 64;
  while (S > 1 && (size_t)(18874368ull + (size_t)S * 1048576ull) > ws_size) S >>= 1;
  int steps = 4096 / S;  // K-steps of 32 per chunk

  hipLaunchKernelGGL(conv_lif_kernel, dim3(16384), dim3(256), 0, stream,
                     x, wconv, out, patt);
  hipLaunchKernelGGL(transpose512, dim3(256), dim3(256), 0, stream, w2, w2t);
  hipLaunchKernelGGL(gemm_kernel, dim3(8 * S), dim3(256), 0, stream,
                     patt, w1, partials, steps);
  if (S >= 8) {
    int G = S / 8;
    hipLaunchKernelGGL(reduce1_kernel, dim3(G * 256), dim3(256), 0, stream,
                       partials, p2);
    hipLaunchKernelGGL(reduce2_kernel, dim3(256), dim3(256), 0, stream,
                       p2, z1, G);
  } else {
    hipLaunchKernelGGL(reduce_kernel, dim3(256), dim3(256), 0, stream,
                       partials, z1, S);
  }
  hipLaunchKernelGGL(fc_kernel, dim3(128), dim3(512), 0, stream,
                     z1, w2t, wout, out);
}